// Round 14
// baseline (368.734 us; speedup 1.0000x reference)
//
#include <hip/hip_runtime.h>
#include <stdint.h>

#define C_IN 128
#define NUMD 524288
#define LNUMD 32768
#define NNUM_DM1 (LNUMD + NUMD/8)
#define PREFIX 16384
#define N_CONV (PREFIX + NNUM_DM1)   // 114688
#define N_EDGES (N_CONV * 7)         // 802816
#define ND8 (NUMD/8)                 // 65536
#define CAP 32
#define EG 12

#define COPY_BLK ((PREFIX+LNUMD)*32/256)     // 6144
#define PREPW_N (114688 + 6272 + 131072)     // w16y + wbias + wd16 = 252032
#define PREPW_BLK ((PREPW_N + 255)/256)      // 985
#define ZERO_BLK 308                         // cnt (458752B) + used (802816B), int4-strided
#define DOWN_BLK (ND8/64)                    // 1024 (4 waves x 16 rows per block)
#define SCAT_BLK (N_EDGES/256)               // 3136

typedef __attribute__((ext_vector_type(8))) short short8;
typedef __attribute__((ext_vector_type(4))) float f32x4;

__device__ inline ushort f2b(float f){
  union { float f; uint32_t u; } v; v.f = f;
  uint32_t r = v.u + 0x7fffu + ((v.u >> 16) & 1u);
  return (ushort)(r >> 16);
}
__device__ inline float b2f_lo(uint32_t u){ union { uint32_t u; float f; } v; v.u = u << 16; return v.f; }
__device__ inline float b2f_hi(uint32_t u){ union { uint32_t u; float f; } v; v.u = u & 0xffff0000u; return v.f; }

// ---- fused: copy prefix+leaf rows | weight conversion | zero cnt+used ----
__global__ void k_prep(const float* __restrict__ x, const float* __restrict__ wconv,
                       const float* __restrict__ wdown,
                       ushort* __restrict__ xconv, ushort* __restrict__ w16y,
                       ushort* __restrict__ wbias, ushort* __restrict__ wd16,
                       int* __restrict__ cnt){
  const int bid = blockIdx.x;
  if (bid < COPY_BLK){
    int gid = bid*256 + threadIdx.x;
    int row = gid >> 5, seg = (gid & 31) * 4;
    int srow, drow;
    if (row < PREFIX){ srow = row; drow = row; }
    else { int k = row - PREFIX; srow = PREFIX + k; drow = PREFIX + 3*k; }
    const float4 f = *(const float4*)(x + (size_t)srow*C_IN + seg);
    ushort4 o; o.x=f2b(f.x); o.y=f2b(f.y); o.z=f2b(f.z); o.w=f2b(f.w);
    *(ushort4*)(xconv + (size_t)drow*C_IN + seg) = o;
  } else if (bid < COPY_BLK + PREPW_BLK){
    int gid = (bid - COPY_BLK)*256 + threadIdx.x;
    if (gid < 114688){
      // w16y[t][o][k] = wconv[(t*135+k)*128 + o]
      int t = gid >> 14, rem = gid & 16383;
      int o = rem >> 7, k = rem & 127;
      w16y[gid] = f2b(wconv[(size_t)(t*135 + k)*128 + o]);
    } else if (gid < 120960){
      // wbias[t][n][o] = wconv[(t*135+128+n)*128 + o]
      int q = gid - 114688;
      int t = q / 896, rem = q % 896;
      int n = rem >> 7, o = rem & 127;
      wbias[q] = f2b(wconv[(size_t)(t*135 + 128 + n)*128 + o]);
    } else if (gid < PREPW_N){
      int i = gid - 120960;
      wd16[i] = f2b(wdown[i]);
    }
  } else {
    // zero cnt[114688 ints] + used[802816 bytes] (contiguous)
    int gid = (bid - COPY_BLK - PREPW_BLK)*256 + threadIdx.x;
    int4 z = {0,0,0,0};
    *(int4*)(cnt + gid*4) = z;
  }
}

// ---- fused: down-projection GEMM (wave-independent, no LDS, no barriers) | scatter ----
__global__ void k_sd(const int* __restrict__ ei, const int* __restrict__ et,
    int* __restrict__ cnt, int* __restrict__ bucket, unsigned char* __restrict__ used,
    const float* __restrict__ x, const ushort* __restrict__ wd16, ushort* __restrict__ xconv){
  const int bid = blockIdx.x;
  if (bid >= DOWN_BLK){
    int e = (bid - DOWN_BLK)*256 + threadIdx.x;
    int r = ei[e], c = ei[N_EDGES + e], t = et[e];
    int key = c*7 + t;
    int pos = atomicAdd(&cnt[r], 1);
    if (pos < CAP) bucket[r*CAP + pos] = key;
    used[key] = 1;                              // plain store: no RMW contention
    return;
  }
  const int tid = threadIdx.x;
  const int w = tid >> 6, lane = tid & 63;
  const int arow = lane & 15, kg = lane >> 4;
  const int n0 = (bid*4 + w) * 16;              // wave-private 16-row tile
  const float* xd = x + (size_t)(PREFIX+LNUMD)*C_IN;
  const float*  asrc = xd  + (size_t)(n0 + arow)*1024 + kg*8;
  const ushort* bsrc = wd16 + (size_t)arow*1024 + kg*8;

  f32x4 acc[8];
  #pragma unroll
  for (int s=0;s<8;s++) acc[s] = (f32x4){0.f,0.f,0.f,0.f};

  float4 af[2][2];
  short8 bb[2][8];
  af[0][0] = *(const float4*)(asrc);
  af[0][1] = *(const float4*)(asrc + 4);
  #pragma unroll
  for (int s=0;s<8;s++) bb[0][s] = *(const short8*)(bsrc + s*16*1024);

  #pragma unroll
  for (int c = 0; c < 32; ++c){
    const int cur = c & 1, nxt = cur ^ 1;
    if (c < 31){
      // prefetch step c+1 (A from HBM, B from L2) — issued BEFORE consuming step c,
      // so every wait below is a counted vmcnt that leaves these in flight
      af[nxt][0] = *(const float4*)(asrc + (c+1)*32);
      af[nxt][1] = *(const float4*)(asrc + (c+1)*32 + 4);
      #pragma unroll
      for (int s=0;s<8;s++) bb[nxt][s] = *(const short8*)(bsrc + s*16*1024 + (c+1)*32);
    }
    // pack A(c) f32 -> bf16x8 in regs
    short8 a;
    uint4 pk;
    pk.x = (uint)f2b(af[cur][0].x) | ((uint)f2b(af[cur][0].y)<<16);
    pk.y = (uint)f2b(af[cur][0].z) | ((uint)f2b(af[cur][0].w)<<16);
    pk.z = (uint)f2b(af[cur][1].x) | ((uint)f2b(af[cur][1].y)<<16);
    pk.w = (uint)f2b(af[cur][1].z) | ((uint)f2b(af[cur][1].w)<<16);
    a = *(short8*)&pk;
    #pragma unroll
    for (int s=0;s<8;s++)
      acc[s] = __builtin_amdgcn_mfma_f32_16x16x32_bf16(a, bb[cur][s], acc[s], 0,0,0);
  }

  #pragma unroll
  for (int s=0;s<8;s++){
    int col = s*16 + arow;
    #pragma unroll
    for (int j=0;j<4;j++){
      int n = n0 + kg*4 + j;                    // C/D: row=(lane>>4)*4+reg
      int i = 3*(n>>1) + 1 + (n&1);             // non-leaf merged index
      xconv[(size_t)(PREFIX + i)*C_IN + col] = f2b(acc[s][j]);
    }
  }
}

// ---- Y[c][t][o] = xconv[c] @ W_t[:128] + W_t[128+nt[c]]; skip unused rows ----
__global__ __launch_bounds__(512) void k_y(const ushort* __restrict__ xconv,
    const ushort* __restrict__ w16y, const ushort* __restrict__ wbias,
    const int* __restrict__ ntype, const unsigned char* __restrict__ used,
    ushort* __restrict__ Y){
  __shared__ ushort As[128*128];    // row*128 + (c16 ^ (row&7))*8
  __shared__ ushort bsh[6272];
  __shared__ int nts[128];
  __shared__ uint usedw[224];
  const int tid = threadIdx.x;
  const int tile = blockIdx.x;
  const unsigned char* usedb = (const unsigned char*)usedw;

  {
    int row = tid >> 2;
    int c0 = (tid & 3) * 4;
    const ushort* src = xconv + ((size_t)tile*128 + row)*128;
    #pragma unroll
    for (int i=0;i<4;i++){
      int c16 = c0 + i;
      uint4 v = *(const uint4*)(src + c16*8);
      *(uint4*)&As[row*128 + ((c16 ^ (row & 7))*8)] = v;
    }
  }
  for (int i = tid; i < 3136; i += 512) ((uint*)bsh)[i] = ((const uint*)wbias)[i];
  if (tid < 128) nts[tid] = ntype[tile*128 + tid];
  if (tid < 224) usedw[tid] = ((const uint*)(used + (size_t)tile*896))[tid];
  __syncthreads();

  const int w = tid >> 6, l = tid & 63;
  const int mg = w >> 2, nc = w & 3;          // 2 row-groups x 4 col-groups
  const int arow = l & 15, kgrp = l >> 4;
  const int obase = nc*32 + arow;

  for (int t = 0; t < 7; ++t){
    f32x4 acc[4][2];
    #pragma unroll
    for (int mf=0;mf<4;mf++){ acc[mf][0]=(f32x4){0,0,0,0}; acc[mf][1]=(f32x4){0,0,0,0}; }
    const ushort* wt = w16y + t*16384;
    #pragma unroll
    for (int kf = 0; kf < 4; ++kf){
      const int kof = kf*32 + kgrp*8;
      short8 b0 = *(const short8*)(wt + (size_t)obase*128 + kof);
      short8 b1 = *(const short8*)(wt + (size_t)(obase+16)*128 + kof);
      #pragma unroll
      for (int mf = 0; mf < 4; ++mf){
        int row = mg*64 + mf*16 + arow;
        int c16 = (kf*4 + kgrp) ^ (row & 7);
        short8 a = *(const short8*)&As[row*128 + c16*8];
        acc[mf][0] = __builtin_amdgcn_mfma_f32_16x16x32_bf16(a, b0, acc[mf][0], 0,0,0);
        acc[mf][1] = __builtin_amdgcn_mfma_f32_16x16x32_bf16(a, b1, acc[mf][1], 0,0,0);
      }
    }
    #pragma unroll
    for (int mf = 0; mf < 4; ++mf){
      #pragma unroll
      for (int j = 0; j < 4; ++j){
        int rl = mg*64 + mf*16 + (l>>4)*4 + j;
        if (usedb[rl*7 + t]){
          int ntv = nts[rl];
          size_t grow = ((size_t)(tile*128 + rl)*7 + t)*128;
          int bb = (t*7 + ntv)*128;
          Y[grow + obase]      = f2b(acc[mf][0][j] + b2f_lo((uint)bsh[bb + obase]));
          Y[grow + obase + 16] = f2b(acc[mf][1][j] + b2f_lo((uint)bsh[bb + obase + 16]));
        }
      }
    }
  }
}

// ---- out[v] = sum over bucket[v] of Y rows (f32 accum); 16 lanes x uint4 ----
__global__ __launch_bounds__(256) void k_gather(const int* __restrict__ cnt,
    const int* __restrict__ bucket, const ushort* __restrict__ Y, float* __restrict__ out){
  const int tid = threadIdx.x;
  const int slot = tid >> 4, lane = tid & 15;
  const int v = blockIdx.x*16 + slot;
  const int n = min(cnt[v], CAP);
  const int* brow = bucket + (size_t)v*CAP;
  float acc[8] = {0.f,0.f,0.f,0.f,0.f,0.f,0.f,0.f};

  int m[EG]; uint4 d[EG];
  const int nb = min(n, EG);
  #pragma unroll
  for (int i=0;i<EG;i++) if (i < nb) m[i] = brow[i];
  #pragma unroll
  for (int i=0;i<EG;i++) if (i < nb)
    d[i] = *(const uint4*)(Y + (size_t)m[i]*C_IN + lane*8);
  #pragma unroll
  for (int i=0;i<EG;i++){
    if (i < nb){
      acc[0] += b2f_lo(d[i].x); acc[1] += b2f_hi(d[i].x);
      acc[2] += b2f_lo(d[i].y); acc[3] += b2f_hi(d[i].y);
      acc[4] += b2f_lo(d[i].z); acc[5] += b2f_hi(d[i].z);
      acc[6] += b2f_lo(d[i].w); acc[7] += b2f_hi(d[i].w);
    }
  }
  for (int e = EG; e < n; e += 4){
    int n4 = min(n - e, 4);
    int m4[4]; uint4 d4[4];
    #pragma unroll
    for (int i=0;i<4;i++) if (i < n4) m4[i] = brow[e + i];
    #pragma unroll
    for (int i=0;i<4;i++) if (i < n4)
      d4[i] = *(const uint4*)(Y + (size_t)m4[i]*C_IN + lane*8);
    #pragma unroll
    for (int i=0;i<4;i++){
      if (i < n4){
        acc[0] += b2f_lo(d4[i].x); acc[1] += b2f_hi(d4[i].x);
        acc[2] += b2f_lo(d4[i].y); acc[3] += b2f_hi(d4[i].y);
        acc[4] += b2f_lo(d4[i].z); acc[5] += b2f_hi(d4[i].z);
        acc[6] += b2f_lo(d4[i].w); acc[7] += b2f_hi(d4[i].w);
      }
    }
  }
  float4 o0; o0.x=acc[0]; o0.y=acc[1]; o0.z=acc[2]; o0.w=acc[3];
  float4 o1; o1.x=acc[4]; o1.y=acc[5]; o1.z=acc[6]; o1.w=acc[7];
  float* dst = out + (size_t)v*C_IN + lane*8;
  *(float4*)dst = o0;
  *(float4*)(dst + 4) = o1;
}

extern "C" void kernel_launch(void* const* d_in, const int* in_sizes, int n_in,
                              void* d_out, int out_size, void* d_ws, size_t ws_size,
                              hipStream_t stream){
  const float* x     = (const float*)d_in[0];
  const int*   ei    = (const int*)d_in[2];
  const int*   et    = (const int*)d_in[3];
  const int*   nt    = (const int*)d_in[4];
  const float* wdown = (const float*)d_in[5];
  const float* wconv = (const float*)d_in[6];
  float* out = (float*)d_out;

  char* p = (char*)d_ws;
  ushort* xconv = (ushort*)p; p += (size_t)N_CONV*C_IN*2;        // 29.36 MB
  ushort* wd16  = (ushort*)p; p += (size_t)128*1024*2;           // 256 KB
  ushort* w16y  = (ushort*)p; p += (size_t)114688*2;             // 224 KB
  ushort* wbias = (ushort*)p; p += 16384;                        // 16 KB
  int* cnt      = (int*)p;    p += (size_t)N_CONV*4;             // 448 KB
  unsigned char* used = (unsigned char*)p; p += 802816;          // 784 KB (zeroed with cnt)
  int* bucket   = (int*)p;    p += (size_t)N_CONV*CAP*4;         // 14.68 MB
  ushort* Y     = (ushort*)p;                                    // 205.5 MB

  k_prep<<<COPY_BLK + PREPW_BLK + ZERO_BLK, 256, 0, stream>>>(x, wconv, wdown, xconv, w16y, wbias, wd16, cnt);
  k_sd<<<DOWN_BLK + SCAT_BLK, 256, 0, stream>>>(ei, et, cnt, bucket, used, x, wd16, xconv);
  k_y<<<N_CONV/128, 512, 0, stream>>>(xconv, w16y, wbias, nt, used, Y);
  k_gather<<<N_CONV/16, 256, 0, stream>>>(cnt, bucket, Y, out);
}

// Round 15
// 366.207 us; speedup vs baseline: 1.0069x; 1.0069x over previous
//
#include <hip/hip_runtime.h>
#include <stdint.h>

#define C_IN 128
#define NUMD 524288
#define LNUMD 32768
#define NNUM_DM1 (LNUMD + NUMD/8)
#define PREFIX 16384
#define N_CONV (PREFIX + NNUM_DM1)   // 114688
#define N_EDGES (N_CONV * 7)         // 802816
#define ND8 (NUMD/8)                 // 65536
#define CAP 32
#define EG 12

#define COPY_BLK ((PREFIX+LNUMD)*32/256)     // 6144
#define PREPW_N (114688 + 6272 + 131072)     // w16y + wbias + wd16 = 252032
#define PREPW_BLK ((PREPW_N + 255)/256)      // 985
#define ZERO_BLK 308                         // cnt (458752B) + used (802816B), int4-strided
#define DOWN_BLK (ND8/128)                   // 512 (128-row tiles, 512 threads)
#define SCAT_BLK (N_EDGES/512)               // 1568

typedef __attribute__((ext_vector_type(8))) short short8;
typedef __attribute__((ext_vector_type(4))) float f32x4;

__device__ inline ushort f2b(float f){
  union { float f; uint32_t u; } v; v.f = f;
  uint32_t r = v.u + 0x7fffu + ((v.u >> 16) & 1u);
  return (ushort)(r >> 16);
}
__device__ inline float b2f_lo(uint32_t u){ union { uint32_t u; float f; } v; v.u = u << 16; return v.f; }
__device__ inline float b2f_hi(uint32_t u){ union { uint32_t u; float f; } v; v.u = u & 0xffff0000u; return v.f; }

#define WAITVM(n) asm volatile("s_waitcnt vmcnt(" #n ")" ::: "memory")

// ---- fused: copy prefix+leaf rows | weight conversion | zero cnt+used ----
__global__ void k_prep(const float* __restrict__ x, const float* __restrict__ wconv,
                       const float* __restrict__ wdown,
                       ushort* __restrict__ xconv, ushort* __restrict__ w16y,
                       ushort* __restrict__ wbias, ushort* __restrict__ wd16,
                       int* __restrict__ cnt){
  const int bid = blockIdx.x;
  if (bid < COPY_BLK){
    int gid = bid*256 + threadIdx.x;
    int row = gid >> 5, seg = (gid & 31) * 4;
    int srow, drow;
    if (row < PREFIX){ srow = row; drow = row; }
    else { int k = row - PREFIX; srow = PREFIX + k; drow = PREFIX + 3*k; }
    const float4 f = *(const float4*)(x + (size_t)srow*C_IN + seg);
    ushort4 o; o.x=f2b(f.x); o.y=f2b(f.y); o.z=f2b(f.z); o.w=f2b(f.w);
    *(ushort4*)(xconv + (size_t)drow*C_IN + seg) = o;
  } else if (bid < COPY_BLK + PREPW_BLK){
    int gid = (bid - COPY_BLK)*256 + threadIdx.x;
    if (gid < 114688){
      // w16y[t][o][k] = wconv[(t*135+k)*128 + o]
      int t = gid >> 14, rem = gid & 16383;
      int o = rem >> 7, k = rem & 127;
      w16y[gid] = f2b(wconv[(size_t)(t*135 + k)*128 + o]);
    } else if (gid < 120960){
      // wbias[t][n][o] = wconv[(t*135+128+n)*128 + o]
      int q = gid - 114688;
      int t = q / 896, rem = q % 896;
      int n = rem >> 7, o = rem & 127;
      wbias[q] = f2b(wconv[(size_t)(t*135 + 128 + n)*128 + o]);
    } else if (gid < PREPW_N){
      int i = gid - 120960;
      wd16[i] = f2b(wdown[i]);
    }
  } else {
    // zero cnt[114688 ints] + used[802816 bytes] (contiguous)
    int gid = (bid - COPY_BLK - PREPW_BLK)*256 + threadIdx.x;
    int4 z = {0,0,0,0};
    *(int4*)(cnt + gid*4) = z;
  }
}

// ---- fused: down-GEMM (global_load_lds staged f32, counted vmcnt, dbuf) | scatter ----
__global__ __launch_bounds__(512) void k_sd(const int* __restrict__ ei, const int* __restrict__ et,
    int* __restrict__ cnt, int* __restrict__ bucket, unsigned char* __restrict__ used,
    const float* __restrict__ x, const ushort* __restrict__ wd16, ushort* __restrict__ xconv){
  const int bid = blockIdx.x;
  if (bid >= DOWN_BLK){
    int e = (bid - DOWN_BLK)*512 + threadIdx.x;
    int r = ei[e], c = ei[N_EDGES + e], t = et[e];
    int key = c*7 + t;
    int pos = atomicAdd(&cnt[r], 1);
    if (pos < CAP) bucket[r*CAP + pos] = key;
    used[key] = 1;
    return;
  }
  __shared__ float Ab[2][128*64];     // f32 chunk; 16B-unit swizzle u^((row&7)<<1)
  const int tid = threadIdx.x;
  const int w = tid >> 6, lane = tid & 63;
  const int arow = lane & 15, kg = lane >> 4;
  const int n0 = bid * 128;
  const float* xd = x + (size_t)(PREFIX+LNUMD)*C_IN;

  // staging geometry: idx = r*512 + tid; row = idx>>4; linear unit u' = idx&15;
  // source unit u = u' ^ ((row&7)<<1)  (inverse swizzle on global source, rule #21)
  int srow_[4], su_[4];
  #pragma unroll
  for (int r=0;r<4;r++){
    int idx = r*512 + tid;
    srow_[r] = idx >> 4;
    su_[r] = (idx & 15) ^ ((srow_[r] & 7) << 1);
  }
  const int wbase = (tid & ~63) << 4;           // wave-uniform LDS byte base per round-0

  #define STAGE(CHUNK, BUF) { \
    _Pragma("unroll") \
    for (int r=0;r<4;r++){ \
      const float* g = xd + (size_t)(n0 + srow_[r])*1024 + (CHUNK)*64 + su_[r]*4; \
      void* l = (char*)&Ab[BUF][0] + (r*8192 + wbase); \
      __builtin_amdgcn_global_load_lds(g, l, 16, 0, 0); \
    } }

  STAGE(0, 0)

  f32x4 acc[8];
  #pragma unroll
  for (int s=0;s<8;s++) acc[s] = (f32x4){0.f,0.f,0.f,0.f};

  const int rloc = w*16 + arow;                 // this lane's A row (0..127)
  const int rsw = (rloc & 7) << 1;

  #pragma unroll
  for (int c = 0; c < 16; ++c){
    // ---- phase 1: B(c) -> regs (older than glds(c+1) in vmcnt FIFO) ----
    short8 br[2][8];
    #pragma unroll
    for (int s=0;s<2;s++)
      #pragma unroll
      for (int cf=0;cf<8;cf++)
        br[s][cf] = *(const short8*)(wd16 + (size_t)(cf*16 + arow)*1024 + c*64 + s*32 + kg*8);
    __builtin_amdgcn_sched_barrier(0);
    // ---- phase 2: stage chunk c+1 (youngest; flies across barrier + MFMA) ----
    if (c < 15) STAGE(c+1, (c+1)&1)
    __builtin_amdgcn_sched_barrier(0);
    // ---- phase 3: drain ONLY chunk c's glds (oldest 4), keep B(c)+glds(c+1) ----
    if (c < 15) { WAITVM(20); } else { WAITVM(16); }
    __builtin_amdgcn_s_barrier();
    __builtin_amdgcn_sched_barrier(0);
    // ---- phase 4: compute from LDS f32 + reg B ----
    #pragma unroll
    for (int s=0;s<2;s++){
      int u0 = s*8 + kg*2;
      const float* p0 = (const float*)((const char*)&Ab[c&1][0] + rloc*256 + ((u0  ) ^ rsw)*16);
      const float* p1 = (const float*)((const char*)&Ab[c&1][0] + rloc*256 + ((u0+1) ^ rsw)*16);
      float4 f0 = *(const float4*)p0;
      float4 f1 = *(const float4*)p1;
      uint4 pk;
      pk.x = (uint)f2b(f0.x) | ((uint)f2b(f0.y)<<16);
      pk.y = (uint)f2b(f0.z) | ((uint)f2b(f0.w)<<16);
      pk.z = (uint)f2b(f1.x) | ((uint)f2b(f1.y)<<16);
      pk.w = (uint)f2b(f1.z) | ((uint)f2b(f1.w)<<16);
      short8 a = *(short8*)&pk;
      #pragma unroll
      for (int cf=0;cf<8;cf++)
        acc[cf] = __builtin_amdgcn_mfma_f32_16x16x32_bf16(a, br[s][cf], acc[cf], 0,0,0);
    }
    // entry barrier for next chunk: all waves' ds_reads done before glds overwrite
    if (c < 15){
      asm volatile("s_waitcnt lgkmcnt(0)" ::: "memory");
      __builtin_amdgcn_s_barrier();
      __builtin_amdgcn_sched_barrier(0);
    }
  }
  #undef STAGE

  #pragma unroll
  for (int cf=0;cf<8;cf++){
    int col = cf*16 + arow;
    #pragma unroll
    for (int j=0;j<4;j++){
      int n = n0 + w*16 + kg*4 + j;
      int i = 3*(n>>1) + 1 + (n&1);
      xconv[(size_t)(PREFIX + i)*C_IN + col] = f2b(acc[cf][j]);
    }
  }
}

// ---- Y[c][t][o] = xconv[c] @ W_t[:128] + W_t[128+nt[c]]; skip unused rows ----
__global__ __launch_bounds__(512) void k_y(const ushort* __restrict__ xconv,
    const ushort* __restrict__ w16y, const ushort* __restrict__ wbias,
    const int* __restrict__ ntype, const unsigned char* __restrict__ used,
    ushort* __restrict__ Y){
  __shared__ ushort As[128*128];    // row*128 + (c16 ^ (row&7))*8
  __shared__ ushort bsh[6272];
  __shared__ int nts[128];
  __shared__ uint usedw[224];
  const int tid = threadIdx.x;
  const int tile = blockIdx.x;
  const unsigned char* usedb = (const unsigned char*)usedw;

  {
    int row = tid >> 2;
    int c0 = (tid & 3) * 4;
    const ushort* src = xconv + ((size_t)tile*128 + row)*128;
    #pragma unroll
    for (int i=0;i<4;i++){
      int c16 = c0 + i;
      uint4 v = *(const uint4*)(src + c16*8);
      *(uint4*)&As[row*128 + ((c16 ^ (row & 7))*8)] = v;
    }
  }
  for (int i = tid; i < 3136; i += 512) ((uint*)bsh)[i] = ((const uint*)wbias)[i];
  if (tid < 128) nts[tid] = ntype[tile*128 + tid];
  if (tid < 224) usedw[tid] = ((const uint*)(used + (size_t)tile*896))[tid];
  __syncthreads();

  const int w = tid >> 6, l = tid & 63;
  const int mg = w >> 2, nc = w & 3;          // 2 row-groups x 4 col-groups
  const int arow = l & 15, kgrp = l >> 4;
  const int obase = nc*32 + arow;

  for (int t = 0; t < 7; ++t){
    f32x4 acc[4][2];
    #pragma unroll
    for (int mf=0;mf<4;mf++){ acc[mf][0]=(f32x4){0,0,0,0}; acc[mf][1]=(f32x4){0,0,0,0}; }
    const ushort* wt = w16y + t*16384;
    #pragma unroll
    for (int kf = 0; kf < 4; ++kf){
      const int kof = kf*32 + kgrp*8;
      short8 b0 = *(const short8*)(wt + (size_t)obase*128 + kof);
      short8 b1 = *(const short8*)(wt + (size_t)(obase+16)*128 + kof);
      #pragma unroll
      for (int mf = 0; mf < 4; ++mf){
        int row = mg*64 + mf*16 + arow;
        int c16 = (kf*4 + kgrp) ^ (row & 7);
        short8 a = *(const short8*)&As[row*128 + c16*8];
        acc[mf][0] = __builtin_amdgcn_mfma_f32_16x16x32_bf16(a, b0, acc[mf][0], 0,0,0);
        acc[mf][1] = __builtin_amdgcn_mfma_f32_16x16x32_bf16(a, b1, acc[mf][1], 0,0,0);
      }
    }
    #pragma unroll
    for (int mf = 0; mf < 4; ++mf){
      #pragma unroll
      for (int j = 0; j < 4; ++j){
        int rl = mg*64 + mf*16 + (l>>4)*4 + j;
        if (usedb[rl*7 + t]){
          int ntv = nts[rl];
          size_t grow = ((size_t)(tile*128 + rl)*7 + t)*128;
          int bb = (t*7 + ntv)*128;
          Y[grow + obase]      = f2b(acc[mf][0][j] + b2f_lo((uint)bsh[bb + obase]));
          Y[grow + obase + 16] = f2b(acc[mf][1][j] + b2f_lo((uint)bsh[bb + obase + 16]));
        }
      }
    }
  }
}

// ---- out[v] = sum over bucket[v] of Y rows (f32 accum); 16 lanes x uint4 ----
__global__ __launch_bounds__(256) void k_gather(const int* __restrict__ cnt,
    const int* __restrict__ bucket, const ushort* __restrict__ Y, float* __restrict__ out){
  const int tid = threadIdx.x;
  const int slot = tid >> 4, lane = tid & 15;
  const int v = blockIdx.x*16 + slot;
  const int n = min(cnt[v], CAP);
  const int* brow = bucket + (size_t)v*CAP;
  float acc[8] = {0.f,0.f,0.f,0.f,0.f,0.f,0.f,0.f};

  int m[EG]; uint4 d[EG];
  const int nb = min(n, EG);
  #pragma unroll
  for (int i=0;i<EG;i++) if (i < nb) m[i] = brow[i];
  #pragma unroll
  for (int i=0;i<EG;i++) if (i < nb)
    d[i] = *(const uint4*)(Y + (size_t)m[i]*C_IN + lane*8);
  #pragma unroll
  for (int i=0;i<EG;i++){
    if (i < nb){
      acc[0] += b2f_lo(d[i].x); acc[1] += b2f_hi(d[i].x);
      acc[2] += b2f_lo(d[i].y); acc[3] += b2f_hi(d[i].y);
      acc[4] += b2f_lo(d[i].z); acc[5] += b2f_hi(d[i].z);
      acc[6] += b2f_lo(d[i].w); acc[7] += b2f_hi(d[i].w);
    }
  }
  for (int e = EG; e < n; e += 4){
    int n4 = min(n - e, 4);
    int m4[4]; uint4 d4[4];
    #pragma unroll
    for (int i=0;i<4;i++) if (i < n4) m4[i] = brow[e + i];
    #pragma unroll
    for (int i=0;i<4;i++) if (i < n4)
      d4[i] = *(const uint4*)(Y + (size_t)m4[i]*C_IN + lane*8);
    #pragma unroll
    for (int i=0;i<4;i++){
      if (i < n4){
        acc[0] += b2f_lo(d4[i].x); acc[1] += b2f_hi(d4[i].x);
        acc[2] += b2f_lo(d4[i].y); acc[3] += b2f_hi(d4[i].y);
        acc[4] += b2f_lo(d4[i].z); acc[5] += b2f_hi(d4[i].z);
        acc[6] += b2f_lo(d4[i].w); acc[7] += b2f_hi(d4[i].w);
      }
    }
  }
  float4 o0; o0.x=acc[0]; o0.y=acc[1]; o0.z=acc[2]; o0.w=acc[3];
  float4 o1; o1.x=acc[4]; o1.y=acc[5]; o1.z=acc[6]; o1.w=acc[7];
  float* dst = out + (size_t)v*C_IN + lane*8;
  *(float4*)dst = o0;
  *(float4*)(dst + 4) = o1;
}

extern "C" void kernel_launch(void* const* d_in, const int* in_sizes, int n_in,
                              void* d_out, int out_size, void* d_ws, size_t ws_size,
                              hipStream_t stream){
  const float* x     = (const float*)d_in[0];
  const int*   ei    = (const int*)d_in[2];
  const int*   et    = (const int*)d_in[3];
  const int*   nt    = (const int*)d_in[4];
  const float* wdown = (const float*)d_in[5];
  const float* wconv = (const float*)d_in[6];
  float* out = (float*)d_out;

  char* p = (char*)d_ws;
  ushort* xconv = (ushort*)p; p += (size_t)N_CONV*C_IN*2;        // 29.36 MB
  ushort* wd16  = (ushort*)p; p += (size_t)128*1024*2;           // 256 KB
  ushort* w16y  = (ushort*)p; p += (size_t)114688*2;             // 224 KB
  ushort* wbias = (ushort*)p; p += 16384;                        // 16 KB
  int* cnt      = (int*)p;    p += (size_t)N_CONV*4;             // 448 KB
  unsigned char* used = (unsigned char*)p; p += 802816;          // 784 KB (zeroed with cnt)
  int* bucket   = (int*)p;    p += (size_t)N_CONV*CAP*4;         // 14.68 MB
  ushort* Y     = (ushort*)p;                                    // 205.5 MB

  k_prep<<<COPY_BLK + PREPW_BLK + ZERO_BLK, 256, 0, stream>>>(x, wconv, wdown, xconv, w16y, wbias, wd16, cnt);
  k_sd<<<DOWN_BLK + SCAT_BLK, 512, 0, stream>>>(ei, et, cnt, bucket, used, x, wd16, xconv);
  k_y<<<N_CONV/128, 512, 0, stream>>>(xconv, w16y, wbias, nt, used, Y);
  k_gather<<<N_CONV/16, 256, 0, stream>>>(cnt, bucket, Y, out);
}

// Round 16
// 336.567 us; speedup vs baseline: 1.0956x; 1.0881x over previous
//
#include <hip/hip_runtime.h>
#include <stdint.h>

#define C_IN 128
#define NUMD 524288
#define LNUMD 32768
#define NNUM_DM1 (LNUMD + NUMD/8)
#define PREFIX 16384
#define N_CONV (PREFIX + NNUM_DM1)   // 114688
#define N_EDGES (N_CONV * 7)         // 802816
#define ND8 (NUMD/8)                 // 65536
#define NPL (PREFIX + LNUMD)         // 49152 prefix+leaf rows (permuted layout)
#define CAP 32
#define EG 12

#define COPY_BLK (NPL*32/256)                // 6144
#define PREPW_N (114688 + 6272 + 131072)     // w16y + wbias + wd16 = 252032
#define PREPW_BLK ((PREPW_N + 255)/256)      // 985
#define ZERO_BLK 308                         // cnt + used, int4-strided
#define DOWN_BLK (ND8/128)                   // 512
#define SCAT_BLK (N_EDGES/512)               // 1568

typedef __attribute__((ext_vector_type(8))) short short8;
typedef __attribute__((ext_vector_type(4))) float f32x4;

__device__ inline ushort f2b(float f){
  union { float f; uint32_t u; } v; v.f = f;
  uint32_t r = v.u + 0x7fffu + ((v.u >> 16) & 1u);
  return (ushort)(r >> 16);
}
__device__ inline float b2f_lo(uint32_t u){ union { uint32_t u; float f; } v; v.u = u << 16; return v.f; }
__device__ inline float b2f_hi(uint32_t u){ union { uint32_t u; float f; } v; v.u = u & 0xffff0000u; return v.f; }

#define BAR_LGKM() do { \
    asm volatile("s_waitcnt lgkmcnt(0)" ::: "memory"); \
    __builtin_amdgcn_s_barrier(); \
    asm volatile("" ::: "memory"); \
  } while(0)

// ---- fused: contiguous copy x[0..NPL) -> xconv | weight conversion | zero cnt+used ----
__global__ void k_prep(const float* __restrict__ x, const float* __restrict__ wconv,
                       const float* __restrict__ wdown,
                       ushort* __restrict__ xconv, ushort* __restrict__ w16y,
                       ushort* __restrict__ wbias, ushort* __restrict__ wd16,
                       int* __restrict__ cnt){
  const int bid = blockIdx.x;
  if (bid < COPY_BLK){
    int gid = bid*256 + threadIdx.x;
    int row = gid >> 5, seg = (gid & 31) * 4;
    const float4 f = *(const float4*)(x + (size_t)row*C_IN + seg);
    ushort4 o; o.x=f2b(f.x); o.y=f2b(f.y); o.z=f2b(f.z); o.w=f2b(f.w);
    *(ushort4*)(xconv + (size_t)row*C_IN + seg) = o;
  } else if (bid < COPY_BLK + PREPW_BLK){
    int gid = (bid - COPY_BLK)*256 + threadIdx.x;
    if (gid < 114688){
      // w16y[t][o][k] = wconv[(t*135+k)*128 + o]
      int t = gid >> 14, rem = gid & 16383;
      int o = rem >> 7, k = rem & 127;
      w16y[gid] = f2b(wconv[(size_t)(t*135 + k)*128 + o]);
    } else if (gid < 120960){
      // wbias[t][n][o] = wconv[(t*135+128+n)*128 + o]
      int q = gid - 114688;
      int t = q / 896, rem = q % 896;
      int n = rem >> 7, o = rem & 127;
      wbias[q] = f2b(wconv[(size_t)(t*135 + 128 + n)*128 + o]);
    } else if (gid < PREPW_N){
      int i = gid - 120960;
      wd16[i] = f2b(wdown[i]);
    }
  } else {
    int gid = (bid - COPY_BLK - PREPW_BLK)*256 + threadIdx.x;
    int4 z = {0,0,0,0};
    *(int4*)(cnt + gid*4) = z;
  }
}

// ---- fused: down-GEMM + fused Y for down rows | edge scatter (permuted keys) ----
__global__ __launch_bounds__(512) void k_sd(const int* __restrict__ ei, const int* __restrict__ et,
    int* __restrict__ cnt, int* __restrict__ bucket, unsigned char* __restrict__ used,
    const float* __restrict__ x, const ushort* __restrict__ wd16,
    const ushort* __restrict__ w16y, const ushort* __restrict__ wbias,
    const int* __restrict__ ntype, ushort* __restrict__ Y){
  const int bid = blockIdx.x;
  if (bid >= DOWN_BLK){
    int e = (bid - DOWN_BLK)*512 + threadIdx.x;
    int r = ei[e], c = ei[N_EDGES + e], t = et[e];
    int pc;
    if (c < PREFIX) pc = c;
    else { int d = c - PREFIX; int q = d/3; int rr = d - q*3;
           pc = (rr == 0) ? PREFIX + q : NPL + 2*q + (rr-1); }
    int key = pc*7 + t;
    int pos = atomicAdd(&cnt[r], 1);
    if (pos < CAP) bucket[r*CAP + pos] = key;
    used[key] = 1;
    return;
  }
  __shared__ ushort As[16384];        // staging / output tile, unit-swizzled
  __shared__ ushort bshs[6272];
  __shared__ int nts[128];
  const int tid = threadIdx.x;
  const int n0 = bid * 128;
  const float* xd = x + (size_t)NPL*C_IN;

  const int srow = tid >> 2, kbase = (tid & 3) * 32;
  const float* src = xd + (size_t)(n0+srow)*1024 + kbase;

  const int w = tid >> 6, l = tid & 63;
  const int mg = w >> 2, nc = w & 3;            // down: 2 row-groups x 4 col-groups
  const int arow = l & 15, kgrp = l >> 4;
  const int obase = nc*32 + arow;

  // stage bias table + node types for this block's down rows (original ids)
  for (int i = tid; i < 3136; i += 512) ((uint*)bshs)[i] = ((const uint*)wbias)[i];
  if (tid < 128){
    int n = n0 + tid;
    nts[tid] = ntype[PREFIX + 3*(n>>1) + 1 + (n&1)];
  }

  f32x4 acc[4][2];
  #pragma unroll
  for (int mf=0;mf<4;mf++){ acc[mf][0]=(f32x4){0,0,0,0}; acc[mf][1]=(f32x4){0,0,0,0}; }

  float4 pf[8];
  #pragma unroll
  for (int i=0;i<8;i++) pf[i] = *(const float4*)(src + i*4);

  for (int c = 0; c < 8; ++c){
    #pragma unroll
    for (int i=0;i<4;i++){
      uint4 pk;
      pk.x = (uint)f2b(pf[2*i].x)   | ((uint)f2b(pf[2*i].y)<<16);
      pk.y = (uint)f2b(pf[2*i].z)   | ((uint)f2b(pf[2*i].w)<<16);
      pk.z = (uint)f2b(pf[2*i+1].x) | ((uint)f2b(pf[2*i+1].y)<<16);
      pk.w = (uint)f2b(pf[2*i+1].z) | ((uint)f2b(pf[2*i+1].w)<<16);
      int slot = (kbase >> 3) + i;
      *(uint4*)&As[srow*128 + ((slot ^ ((srow & 7) << 1)) << 3)] = pk;
    }
    BAR_LGKM();                                 // LDS visible; vmcnt untouched
    short8 breg[8];
    #pragma unroll
    for (int kf=0;kf<4;kf++){
      const ushort* bp = wd16 + c*128 + kf*32 + kgrp*8;
      breg[kf*2]   = *(const short8*)(bp + (size_t)obase*1024);
      breg[kf*2+1] = *(const short8*)(bp + (size_t)(obase+16)*1024);
    }
    __builtin_amdgcn_sched_barrier(0);
    if (c < 7){
      const float* s2 = src + (c+1)*128;
      #pragma unroll
      for (int i=0;i<8;i++) pf[i] = *(const float4*)(s2 + i*4);
    }
    __builtin_amdgcn_sched_barrier(0);
    #pragma unroll
    for (int kf=0;kf<4;kf++){
      #pragma unroll
      for (int mf=0;mf<4;mf++){
        int row = mg*64 + mf*16 + arow;
        int slot = (kf*4 + kgrp) ^ ((arow & 7) << 1);
        short8 a = *(const short8*)&As[row*128 + (slot << 3)];
        acc[mf][0] = __builtin_amdgcn_mfma_f32_16x16x32_bf16(a, breg[kf*2],   acc[mf][0], 0,0,0);
        acc[mf][1] = __builtin_amdgcn_mfma_f32_16x16x32_bf16(a, breg[kf*2+1], acc[mf][1], 0,0,0);
      }
    }
    BAR_LGKM();                                 // protect As before next pack
  }

  // ---- write down output tile (bf16) back into As, same unit-swizzle ----
  #pragma unroll
  for (int mf = 0; mf < 4; ++mf){
    #pragma unroll
    for (int side = 0; side < 2; ++side){
      int col = obase + side*16;
      int u = col >> 3;
      #pragma unroll
      for (int j = 0; j < 4; ++j){
        int row = mg*64 + mf*16 + kgrp*4 + j;
        As[row*128 + ((u ^ ((row & 7) << 1)) << 3) + (arow & 7)] = f2b(acc[mf][side][j]);
      }
    }
  }
  BAR_LGKM();

  // ---- fused Y pass: Y[q][t] = tile @ W_t + bias, q = NPL + n0 + rl ----
  const size_t yb = (size_t)NPL + n0;
  for (int t = 0; t < 7; ++t){
    const ushort* wt = w16y + t*16384;
    f32x4 ay[8];
    #pragma unroll
    for (int s=0;s<8;s++) ay[s] = (f32x4){0.f,0.f,0.f,0.f};
    #pragma unroll
    for (int kf = 0; kf < 4; ++kf){
      int row = 16*w + arow;
      int u = (kf*4 + kgrp) ^ ((row & 7) << 1);
      short8 a = *(const short8*)&As[row*128 + (u << 3)];
      #pragma unroll
      for (int s = 0; s < 8; ++s){
        short8 b = *(const short8*)(wt + (size_t)(s*16 + arow)*128 + kf*32 + kgrp*8);
        ay[s] = __builtin_amdgcn_mfma_f32_16x16x32_bf16(a, b, ay[s], 0,0,0);
      }
    }
    #pragma unroll
    for (int s = 0; s < 8; ++s){
      int col = s*16 + arow;
      #pragma unroll
      for (int j = 0; j < 4; ++j){
        int rl = 16*w + kgrp*4 + j;
        int ntv = nts[rl];
        Y[((yb + rl)*7 + t)*128 + col] =
          f2b(ay[s][j] + b2f_lo((uint)bshs[(t*7 + ntv)*128 + col]));
      }
    }
  }
}

// ---- Y for prefix+leaf rows (384 tiles); skip unused rows ----
__global__ __launch_bounds__(512) void k_y(const ushort* __restrict__ xconv,
    const ushort* __restrict__ w16y, const ushort* __restrict__ wbias,
    const int* __restrict__ ntype, const unsigned char* __restrict__ used,
    ushort* __restrict__ Y){
  __shared__ ushort As[128*128];    // row*128 + (c16 ^ (row&7))*8
  __shared__ ushort bsh[6272];
  __shared__ int nts[128];
  __shared__ uint usedw[224];
  const int tid = threadIdx.x;
  const int tile = blockIdx.x;
  const unsigned char* usedb = (const unsigned char*)usedw;

  {
    int row = tid >> 2;
    int c0 = (tid & 3) * 4;
    const ushort* src = xconv + ((size_t)tile*128 + row)*128;
    #pragma unroll
    for (int i=0;i<4;i++){
      int c16 = c0 + i;
      uint4 v = *(const uint4*)(src + c16*8);
      *(uint4*)&As[row*128 + ((c16 ^ (row & 7))*8)] = v;
    }
  }
  for (int i = tid; i < 3136; i += 512) ((uint*)bsh)[i] = ((const uint*)wbias)[i];
  if (tid < 128){
    int g = tile*128 + tid;                    // permuted row -> original vertex id
    nts[tid] = ntype[g < PREFIX ? g : PREFIX + 3*(g - PREFIX)];
  }
  if (tid < 224) usedw[tid] = ((const uint*)(used + (size_t)tile*896))[tid];
  __syncthreads();

  const int w = tid >> 6, l = tid & 63;
  const int mg = w >> 2, nc = w & 3;
  const int arow = l & 15, kgrp = l >> 4;
  const int obase = nc*32 + arow;

  for (int t = 0; t < 7; ++t){
    f32x4 acc[4][2];
    #pragma unroll
    for (int mf=0;mf<4;mf++){ acc[mf][0]=(f32x4){0,0,0,0}; acc[mf][1]=(f32x4){0,0,0,0}; }
    const ushort* wt = w16y + t*16384;
    #pragma unroll
    for (int kf = 0; kf < 4; ++kf){
      const int kof = kf*32 + kgrp*8;
      short8 b0 = *(const short8*)(wt + (size_t)obase*128 + kof);
      short8 b1 = *(const short8*)(wt + (size_t)(obase+16)*128 + kof);
      #pragma unroll
      for (int mf = 0; mf < 4; ++mf){
        int row = mg*64 + mf*16 + arow;
        int c16 = (kf*4 + kgrp) ^ (row & 7);
        short8 a = *(const short8*)&As[row*128 + c16*8];
        acc[mf][0] = __builtin_amdgcn_mfma_f32_16x16x32_bf16(a, b0, acc[mf][0], 0,0,0);
        acc[mf][1] = __builtin_amdgcn_mfma_f32_16x16x32_bf16(a, b1, acc[mf][1], 0,0,0);
      }
    }
    #pragma unroll
    for (int mf = 0; mf < 4; ++mf){
      #pragma unroll
      for (int j = 0; j < 4; ++j){
        int rl = mg*64 + mf*16 + (l>>4)*4 + j;
        if (usedb[rl*7 + t]){
          int ntv = nts[rl];
          size_t grow = ((size_t)(tile*128 + rl)*7 + t)*128;
          int bb = (t*7 + ntv)*128;
          Y[grow + obase]      = f2b(acc[mf][0][j] + b2f_lo((uint)bsh[bb + obase]));
          Y[grow + obase + 16] = f2b(acc[mf][1][j] + b2f_lo((uint)bsh[bb + obase + 16]));
        }
      }
    }
  }
}

// ---- out[v] = sum over bucket[v] of Y rows (f32 accum); 16 lanes x uint4 ----
__global__ __launch_bounds__(256) void k_gather(const int* __restrict__ cnt,
    const int* __restrict__ bucket, const ushort* __restrict__ Y, float* __restrict__ out){
  const int tid = threadIdx.x;
  const int slot = tid >> 4, lane = tid & 15;
  const int v = blockIdx.x*16 + slot;
  const int n = min(cnt[v], CAP);
  const int* brow = bucket + (size_t)v*CAP;
  float acc[8] = {0.f,0.f,0.f,0.f,0.f,0.f,0.f,0.f};

  int m[EG]; uint4 d[EG];
  const int nb = min(n, EG);
  #pragma unroll
  for (int i=0;i<EG;i++) if (i < nb) m[i] = brow[i];
  #pragma unroll
  for (int i=0;i<EG;i++) if (i < nb)
    d[i] = *(const uint4*)(Y + (size_t)m[i]*C_IN + lane*8);
  #pragma unroll
  for (int i=0;i<EG;i++){
    if (i < nb){
      acc[0] += b2f_lo(d[i].x); acc[1] += b2f_hi(d[i].x);
      acc[2] += b2f_lo(d[i].y); acc[3] += b2f_hi(d[i].y);
      acc[4] += b2f_lo(d[i].z); acc[5] += b2f_hi(d[i].z);
      acc[6] += b2f_lo(d[i].w); acc[7] += b2f_hi(d[i].w);
    }
  }
  for (int e = EG; e < n; e += 4){
    int n4 = min(n - e, 4);
    int m4[4]; uint4 d4[4];
    #pragma unroll
    for (int i=0;i<4;i++) if (i < n4) m4[i] = brow[e + i];
    #pragma unroll
    for (int i=0;i<4;i++) if (i < n4)
      d4[i] = *(const uint4*)(Y + (size_t)m4[i]*C_IN + lane*8);
    #pragma unroll
    for (int i=0;i<4;i++){
      if (i < n4){
        acc[0] += b2f_lo(d4[i].x); acc[1] += b2f_hi(d4[i].x);
        acc[2] += b2f_lo(d4[i].y); acc[3] += b2f_hi(d4[i].y);
        acc[4] += b2f_lo(d4[i].z); acc[5] += b2f_hi(d4[i].z);
        acc[6] += b2f_lo(d4[i].w); acc[7] += b2f_hi(d4[i].w);
      }
    }
  }
  float4 o0; o0.x=acc[0]; o0.y=acc[1]; o0.z=acc[2]; o0.w=acc[3];
  float4 o1; o1.x=acc[4]; o1.y=acc[5]; o1.z=acc[6]; o1.w=acc[7];
  float* dst = out + (size_t)v*C_IN + lane*8;
  *(float4*)dst = o0;
  *(float4*)(dst + 4) = o1;
}

extern "C" void kernel_launch(void* const* d_in, const int* in_sizes, int n_in,
                              void* d_out, int out_size, void* d_ws, size_t ws_size,
                              hipStream_t stream){
  const float* x     = (const float*)d_in[0];
  const int*   ei    = (const int*)d_in[2];
  const int*   et    = (const int*)d_in[3];
  const int*   nt    = (const int*)d_in[4];
  const float* wdown = (const float*)d_in[5];
  const float* wconv = (const float*)d_in[6];
  float* out = (float*)d_out;

  char* p = (char*)d_ws;
  ushort* xconv = (ushort*)p; p += (size_t)N_CONV*C_IN*2;        // 29.36 MB (only NPL used)
  ushort* wd16  = (ushort*)p; p += (size_t)128*1024*2;           // 256 KB
  ushort* w16y  = (ushort*)p; p += (size_t)114688*2;             // 224 KB
  ushort* wbias = (ushort*)p; p += 16384;                        // 16 KB
  int* cnt      = (int*)p;    p += (size_t)N_CONV*4;             // 448 KB
  unsigned char* used = (unsigned char*)p; p += 802816;          // 784 KB (zeroed with cnt)
  int* bucket   = (int*)p;    p += (size_t)N_CONV*CAP*4;         // 14.68 MB
  ushort* Y     = (ushort*)p;                                    // 205.5 MB

  k_prep<<<COPY_BLK + PREPW_BLK + ZERO_BLK, 256, 0, stream>>>(x, wconv, wdown, xconv, w16y, wbias, wd16, cnt);
  k_sd<<<DOWN_BLK + SCAT_BLK, 512, 0, stream>>>(ei, et, cnt, bucket, used, x, wd16, w16y, wbias, nt, Y);
  k_y<<<NPL/128, 512, 0, stream>>>(xconv, w16y, wbias, nt, used, Y);
  k_gather<<<N_CONV/16, 256, 0, stream>>>(cnt, bucket, Y, out);
}